// Round 6
// baseline (230.642 us; speedup 1.0000x reference)
//
#include <hip/hip_runtime.h>

// Problem constants (from reference)
#define BB      2
#define CC      256
#define HH      384
#define WW      384
#define N_ACT   16384
#define GRID_N  192                  // index grid; coord = 2*idx (OFFSET=0, STRIDE=2)
#define NCELL   (GRID_N * GRID_N)    // 36864
#define PLANE_F4 ((HH * WW) / 4)     // 36864 float4 per (b,c) plane
#define ROW_F4   (WW / 4)            // 96 float4 per row
#define PAIRS_PER_PLANE (PLANE_F4 / 2)   // 18432 row-pair float4 slots
#define SCAN_T  1024
#define CPT     (NCELL / SCAN_T)     // 36 cells per scan thread

// Native clang vector type — required by __builtin_nontemporal_load.
typedef float fx4 __attribute__((ext_vector_type(4)));

// --- Kernel 1: winner[cell] = max k writing to that cell (numpy last-wins) --
__global__ void winner_scatter_kernel(const int2* __restrict__ idx,
                                      int* __restrict__ winner) {
    int k = blockIdx.x * blockDim.x + threadIdx.x;
    if (k < N_ACT) {
        int2 p = idx[k];                        // p.x = iy, p.y = ix
        atomicMax(&winner[p.x * GRID_N + p.y], k);
    }
}

// --- Kernel 2: single-block scan: packed[cell] = (winner<<16)|rank, or -1 ---
// rank = exclusive prefix count of active cells in raster order.
__global__ void __launch_bounds__(SCAN_T)
scan_kernel(const int* __restrict__ winner, int* __restrict__ packed) {
    __shared__ int s[SCAN_T];
    int t = threadIdx.x;
    int base = t * CPT;

    int w[CPT];
    int cnt = 0;
#pragma unroll
    for (int i = 0; i < CPT; ++i) {
        w[i] = winner[base + i];
        cnt += (w[i] >= 0);
    }
    s[t] = cnt;
    __syncthreads();
    // Hillis-Steele inclusive scan over 1024 partial counts
    for (int off = 1; off < SCAN_T; off <<= 1) {
        int v = (t >= off) ? s[t - off] : 0;
        __syncthreads();
        s[t] += v;
        __syncthreads();
    }
    int rank = s[t] - cnt;                      // exclusive base for this thread
#pragma unroll
    for (int i = 0; i < CPT; ++i) {
        int wi = w[i];
        packed[base + i] = (wi >= 0) ? ((wi << 16) | rank) : -1;
        rank += (wi >= 0);
    }
}

// --- Kernel 3: build compacted values xs[bc][rank] = x[bc][winner] ----------
// Coalesced read of x; scattered write confined to a 53KB L2-resident window.
__global__ void build_xs_kernel(const float* __restrict__ x,
                                const int2* __restrict__ idx,
                                const int* __restrict__ packed,
                                float* __restrict__ xs) {
    int bc = blockIdx.y;
    int k  = blockIdx.x * blockDim.x + threadIdx.x;   // 0..16383
    int2 p = idx[k];
    int pk = packed[p.x * GRID_N + p.y];
    if (pk != -1 && (pk >> 16) == k)
        xs[bc * N_ACT + (pk & 0xFFFF)] = x[bc * N_ACT + k];
}

// --- Kernel 4: fused copy + patch, one thread per row-pair float4 -----------
// Gather is now xs[base+rank]: a wave's gathers span ~46 consecutive floats
// (2-3 cache lines) instead of ~46 random lines.
__global__ void scatter_main_kernel(const fx4* __restrict__ orig,
                                    const float* __restrict__ xs,
                                    const int* __restrict__ packed,
                                    fx4* __restrict__ out) {
    int bc = blockIdx.y;                                   // 0..511
    int q  = blockIdx.x * blockDim.x + threadIdx.x;        // 0..18431
    int gy  = q / ROW_F4;                                  // grid row 0..191
    int col = q - gy * ROW_F4;                             // float4 col 0..95

    int base = bc * PLANE_F4 + (gy * 2) * ROW_F4 + col;    // even row slot

    const int2* prow2 = reinterpret_cast<const int2*>(packed + gy * GRID_N);
    int2 pk = prow2[col];                                  // cells 2col, 2col+1
    fx4 ve = __builtin_nontemporal_load(&orig[base]);
    fx4 vo = __builtin_nontemporal_load(&orig[base + ROW_F4]);

    const float* xsp = xs + bc * N_ACT;
    if (pk.x != -1) ve[0] = xsp[pk.x & 0xFFFF];
    if (pk.y != -1) ve[2] = xsp[pk.y & 0xFFFF];

    out[base] = ve;
    out[base + ROW_F4] = vo;
}

extern "C" void kernel_launch(void* const* d_in, const int* in_sizes, int n_in,
                              void* d_out, int out_size, void* d_ws, size_t ws_size,
                              hipStream_t stream) {
    const float* x    = (const float*)d_in[0];   // [B, C, N_ACT]
    const float* orig = (const float*)d_in[1];   // [B, C, H, W]
    const int*   idx  = (const int*)d_in[2];     // [N_ACT, 2]
    float*       out  = (float*)d_out;           // [B, C, H, W]

    char* ws = (char*)d_ws;
    int*   winner = (int*)ws;                          // 36864 ints
    int*   packed = (int*)(ws + NCELL * 4);            // 36864 ints
    float* xs     = (float*)(ws + 2 * NCELL * 4);      // 512*16384 floats (33.5MB)

    // 1. winner map = -1 (0xFF bytes)
    (void)hipMemsetAsync(winner, 0xFF, NCELL * sizeof(int), stream);
    // 2. last-write-wins via atomicMax over k
    winner_scatter_kernel<<<dim3((N_ACT + 255) / 256), dim3(256), 0, stream>>>(
        (const int2*)idx, winner);
    // 3. rank scan -> packed winner|rank map
    scan_kernel<<<dim3(1), dim3(SCAN_T), 0, stream>>>(winner, packed);
    // 4. compact winning values (coalesced x read)
    build_xs_kernel<<<dim3(N_ACT / 256, BB * CC), dim3(256), 0, stream>>>(
        x, (const int2*)idx, packed, xs);
    // 5. fused copy + patch with rank-local gathers
    scatter_main_kernel<<<dim3(PAIRS_PER_PLANE / 256, BB * CC), dim3(256), 0, stream>>>(
        (const fx4*)orig, xs, packed, (fx4*)out);
}

// Round 7
// 142.965 us; speedup vs baseline: 1.6133x; 1.6133x over previous
//
#include <hip/hip_runtime.h>

// Problem constants (from reference)
#define BB      2
#define CC      256
#define HH      384
#define WW      384
#define N_ACT   16384
#define GRID_N  192                  // index grid; coord = 2*idx (OFFSET=0, STRIDE=2)
#define NCELL   (GRID_N * GRID_N)
#define PLANE_F4 ((HH * WW) / 4)     // 36864 float4 per (b,c) plane
#define ROW_F4   (WW / 4)            // 96 float4 per row
#define PAIRS_PER_PLANE (PLANE_F4 / 2)   // 18432 row-pair float4 slots
#define BLK_PER_PLANE (PAIRS_PER_PLANE / 256)  // 72
#define NXCD    8

// Native clang vector type — required by __builtin_nontemporal_load.
typedef float fx4 __attribute__((ext_vector_type(4)));

// --- Kernel 1: winner[cell] = max k writing to that cell (numpy last-wins) --
__global__ void winner_scatter_kernel(const int2* __restrict__ idx,
                                      int* __restrict__ winner) {
    int k = blockIdx.x * blockDim.x + threadIdx.x;
    if (k < N_ACT) {
        int2 p = idx[k];                        // p.x = iy, p.y = ix
        atomicMax(&winner[p.x * GRID_N + p.y], k);
    }
}

// --- Kernel 2: fused copy + patch, XCD-local planes -------------------------
// 1-D grid of 512*72 blocks. Linear block id L dispatches round-robin over
// the 8 XCDs; we decode L so that ALL 72 blocks of a plane share L%8 -> one
// XCD, so each plane's 64KB x-slice and the 147KB winner map are fetched
// into that XCD's L2 once and every gather is an L2 hit.
__global__ void scatter_main_kernel(const fx4* __restrict__ orig,
                                    const float* __restrict__ x,
                                    const int* __restrict__ winner,
                                    fx4* __restrict__ out) {
    int L   = blockIdx.x;
    int xcd = L & (NXCD - 1);
    int g   = L >> 3;                      // 0..4607
    int p   = (g / BLK_PER_PLANE) * NXCD + xcd;   // plane 0..511
    int j   = g % BLK_PER_PLANE;                  // block-in-plane 0..71

    int q   = j * 256 + threadIdx.x;       // row-pair slot 0..18431
    int gy  = q / ROW_F4;                  // grid row 0..191
    int col = q - gy * ROW_F4;             // float4 col 0..95

    int base = p * PLANE_F4 + (gy * 2) * ROW_F4 + col;   // even row slot

    // Independent loads issued together: winner pair, two stream float4s.
    const int2* wrow2 = reinterpret_cast<const int2*>(winner + gy * GRID_N);
    int2 w = wrow2[col];                   // cells gx=2col, 2col+1
    fx4 ve = __builtin_nontemporal_load(&orig[base]);
    fx4 vo = __builtin_nontemporal_load(&orig[base + ROW_F4]);

    // Unconditional clamped gathers (L2-local after swizzle); select later.
    const float* xp = x + p * N_ACT;
    float g0 = xp[w.x & (N_ACT - 1)];
    float g1 = xp[w.y & (N_ACT - 1)];
    ve[0] = (w.x >= 0) ? g0 : ve[0];
    ve[2] = (w.y >= 0) ? g1 : ve[2];

    out[base] = ve;
    out[base + ROW_F4] = vo;
}

extern "C" void kernel_launch(void* const* d_in, const int* in_sizes, int n_in,
                              void* d_out, int out_size, void* d_ws, size_t ws_size,
                              hipStream_t stream) {
    const float* x    = (const float*)d_in[0];   // [B, C, N_ACT]
    const float* orig = (const float*)d_in[1];   // [B, C, H, W]
    const int*   idx  = (const int*)d_in[2];     // [N_ACT, 2]
    float*       out  = (float*)d_out;           // [B, C, H, W]
    int*         winner = (int*)d_ws;            // NCELL ints = 147456 B

    // 1. winner map = -1 (0xFF bytes) — async memset is graph-capturable
    (void)hipMemsetAsync(winner, 0xFF, NCELL * sizeof(int), stream);
    // 2. last-write-wins via atomicMax over k
    winner_scatter_kernel<<<dim3((N_ACT + 255) / 256), dim3(256), 0, stream>>>(
        (const int2*)idx, winner);
    // 3. fused copy + patch, XCD-local planes
    scatter_main_kernel<<<dim3(BB * CC * BLK_PER_PLANE), dim3(256), 0, stream>>>(
        (const fx4*)orig, x, winner, (fx4*)out);
}

// Round 8
// 129.910 us; speedup vs baseline: 1.7754x; 1.1005x over previous
//
#include <hip/hip_runtime.h>

// Problem constants (from reference)
#define BB      2
#define CC      256
#define HH      384
#define WW      384
#define N_ACT   16384
#define GRID_N  192                  // index grid; coord = 2*idx (OFFSET=0, STRIDE=2)
#define NCELL   (GRID_N * GRID_N)
#define PLANE_F4 ((HH * WW) / 4)     // 36864 float4 per (b,c) plane
#define ROW_F4   (WW / 4)            // 96 float4 per row
#define PAIRS_PER_PLANE (PLANE_F4 / 2)   // 18432 row-pair float4 slots
#define BLK_PER_PLANE (PAIRS_PER_PLANE / 256)  // 72
#define NXCD    8

// Native clang vector type — required by __builtin_nontemporal_load/store.
typedef float fx4 __attribute__((ext_vector_type(4)));

// --- Kernel 1: winner[cell] = max k writing to that cell (numpy last-wins) --
__global__ void winner_scatter_kernel(const int2* __restrict__ idx,
                                      int* __restrict__ winner) {
    int k = blockIdx.x * blockDim.x + threadIdx.x;
    if (k < N_ACT) {
        int2 p = idx[k];                        // p.x = iy, p.y = ix
        atomicMax(&winner[p.x * GRID_N + p.y], k);
    }
}

// --- Kernel 2: fused copy + patch, r3 structure + XCD-local planes ----------
// All 72 blocks of plane p share L%8 == p%8, so under round-robin block->XCD
// dispatch each plane's 64KB x-slice lands in exactly one XCD's L2; gathers
// become warm-L2 hits instead of L3 round-trips replicated on 8 XCDs.
// NT loads (orig read-once) + NT stores (r3-vs-r5: NT stores were faster).
// Branchy exec-masked gathers: only ~35% of cells are active; clamped
// unconditional gathers (r7) cost ~2.9x gather traffic — don't.
__global__ void scatter_main_kernel(const fx4* __restrict__ orig,
                                    const float* __restrict__ x,
                                    const int* __restrict__ winner,
                                    fx4* __restrict__ out) {
    int L   = blockIdx.x;
    int xcd = L & (NXCD - 1);
    int g   = L >> 3;                             // 0..4607
    int p   = (g / BLK_PER_PLANE) * NXCD + xcd;   // plane 0..511
    int j   = g % BLK_PER_PLANE;                  // block-in-plane 0..71

    int q   = j * 256 + threadIdx.x;              // row-pair slot 0..18431
    int gy  = q / ROW_F4;                         // grid row 0..191
    int col = q - gy * ROW_F4;                    // float4 col 0..95

    int base = p * PLANE_F4 + (gy * 2) * ROW_F4 + col;   // even row slot

    // Independent loads issued together: winner pair + two stream float4s.
    const int2* wrow2 = reinterpret_cast<const int2*>(winner + gy * GRID_N);
    int2 w = wrow2[col];                          // cells gx=2col, 2col+1
    fx4 ve = __builtin_nontemporal_load(&orig[base]);
    fx4 vo = __builtin_nontemporal_load(&orig[base + ROW_F4]);

    if (w.x >= 0 || w.y >= 0) {
        const float* xp = x + p * N_ACT;
        if (w.x >= 0) ve[0] = xp[w.x];
        if (w.y >= 0) ve[2] = xp[w.y];
    }

    __builtin_nontemporal_store(ve, &out[base]);
    __builtin_nontemporal_store(vo, &out[base + ROW_F4]);
}

extern "C" void kernel_launch(void* const* d_in, const int* in_sizes, int n_in,
                              void* d_out, int out_size, void* d_ws, size_t ws_size,
                              hipStream_t stream) {
    const float* x    = (const float*)d_in[0];   // [B, C, N_ACT]
    const float* orig = (const float*)d_in[1];   // [B, C, H, W]
    const int*   idx  = (const int*)d_in[2];     // [N_ACT, 2]
    float*       out  = (float*)d_out;           // [B, C, H, W]
    int*         winner = (int*)d_ws;            // NCELL ints = 147456 B

    // 1. winner map = -1 (0xFF bytes) — async memset is graph-capturable
    (void)hipMemsetAsync(winner, 0xFF, NCELL * sizeof(int), stream);
    // 2. last-write-wins via atomicMax over k
    winner_scatter_kernel<<<dim3((N_ACT + 255) / 256), dim3(256), 0, stream>>>(
        (const int2*)idx, winner);
    // 3. fused copy + patch, XCD-local planes
    scatter_main_kernel<<<dim3(BB * CC * BLK_PER_PLANE), dim3(256), 0, stream>>>(
        (const fx4*)orig, x, winner, (fx4*)out);
}